// Round 9
// baseline (346.964 us; speedup 1.0000x reference)
//
#include <hip/hip_runtime.h>
#include <hip/hip_fp16.h>
#include <math.h>

#define N_NODES 100000
#define N_EDGES 400000
#define HDIM    128
#define NSLICE  8
#define SDIM    16                    // dims per slice
#define KP1     6
#define RMS_EPS 1.1920929e-07f

#define SCAN_B  256
#define N_SCAN_BLOCKS ((N_NODES + SCAN_B - 1) / SCAN_B)   // 391

// native clang vector type for nontemporal builtins
typedef int intx4 __attribute__((ext_vector_type(4)));

// slice stride in elements
#define SS ((size_t)N_NODES * SDIM)

// ---------------------------------------------------------------------------
// x (row-major f32) -> xh (slice-major fp16): 16 lanes per node, 8 dims/lane
// ---------------------------------------------------------------------------
__global__ __launch_bounds__(256)
void x2h_slice_kernel(const float* __restrict__ x, __half* __restrict__ xh) {
    int t = blockIdx.x * 256 + threadIdx.x;
    int n = t >> 4;
    int l = t & 15;
    if (n >= N_NODES) return;
    int s = l >> 1, h = l & 1;
    const float4* px = reinterpret_cast<const float4*>(x + (size_t)n * HDIM + l * 8);
    float4 a = px[0], b = px[1];
    int4 r;
    __half2* hh = reinterpret_cast<__half2*>(&r);
    hh[0] = __floats2half2_rn(a.x, a.y);
    hh[1] = __floats2half2_rn(a.z, a.w);
    hh[2] = __floats2half2_rn(b.x, b.y);
    hh[3] = __floats2half2_rn(b.z, b.w);
    *reinterpret_cast<int4*>(xh + (size_t)s * SS + (size_t)n * SDIM + h * 8) = r;
}

// ---------------------------------------------------------------------------
// CSR build (identical to r8 structure; fill packs src|w into 4 bytes)
// ---------------------------------------------------------------------------
__global__ void hist_kernel(const int* __restrict__ dst, int* __restrict__ deg) {
    int e = blockIdx.x * blockDim.x + threadIdx.x;
    if (e >= N_EDGES) return;
    atomicAdd(&deg[dst[e]], 1);
}

__global__ void scan_local_kernel(const int* __restrict__ deg,
                                  int* __restrict__ inc,
                                  int* __restrict__ blockSums) {
    __shared__ int lds[SCAN_B];
    int i = blockIdx.x * SCAN_B + threadIdx.x;
    int v = (i < N_NODES) ? deg[i] : 0;
    lds[threadIdx.x] = v;
    __syncthreads();
    #pragma unroll
    for (int off = 1; off < SCAN_B; off <<= 1) {
        int t = (threadIdx.x >= off) ? lds[threadIdx.x - off] : 0;
        __syncthreads();
        lds[threadIdx.x] += t;
        __syncthreads();
    }
    if (i < N_NODES) inc[i] = lds[threadIdx.x];
    if (threadIdx.x == SCAN_B - 1) blockSums[blockIdx.x] = lds[SCAN_B - 1];
}

__global__ void scan_blocks_kernel(int* __restrict__ blockSums) {
    __shared__ int lds[512];
    int v = (threadIdx.x < N_SCAN_BLOCKS) ? blockSums[threadIdx.x] : 0;
    lds[threadIdx.x] = v;
    __syncthreads();
    #pragma unroll
    for (int off = 1; off < 512; off <<= 1) {
        int t = ((int)threadIdx.x >= off) ? lds[threadIdx.x - off] : 0;
        __syncthreads();
        lds[threadIdx.x] += t;
        __syncthreads();
    }
    if (threadIdx.x < N_SCAN_BLOCKS)
        blockSums[threadIdx.x] = (threadIdx.x == 0) ? 0 : lds[threadIdx.x - 1];
}

__global__ void finalize_kernel(const int* __restrict__ deg,
                                const int* __restrict__ inc,
                                const int* __restrict__ blockSums,
                                int* __restrict__ rowptr,
                                int* __restrict__ cursor) {
    int i = blockIdx.x * SCAN_B + threadIdx.x;
    if (i >= N_NODES) return;
    int ex = inc[i] - deg[i] + blockSums[i >> 8];
    rowptr[i] = ex;
    cursor[i] = ex;
    if (i == 0) rowptr[N_NODES] = N_EDGES;
}

// pack: {src:17 bits}<<15 | {w fixed-point 15 bits}; w err <= 3e-5
__global__ void fill_kernel(const int* __restrict__ src,
                            const int* __restrict__ dst,
                            const float* __restrict__ ew,
                            int* __restrict__ cursor,
                            int* __restrict__ epk) {
    int e = blockIdx.x * blockDim.x + threadIdx.x;
    if (e >= N_EDGES) return;
    int d = dst[e];
    int pos = atomicAdd(&cursor[d], 1);
    int wf = (int)(ew[e] * 32768.0f);
    if (wf > 32767) wf = 32767;
    if (wf < 0) wf = 0;
    unsigned p = ((unsigned)src[e] << 15) | (unsigned)wf;
    epk[pos] = (int)p;
}

// ---------------------------------------------------------------------------
// helpers
// ---------------------------------------------------------------------------
__device__ __forceinline__ void gfma(const __half* sb, int p, float* S) {
    int m = ((unsigned)p) >> 15;
    float w = (float)(p & 32767) * (1.0f / 32768.0f);
    const int4* q = reinterpret_cast<const int4*>(sb + (size_t)m * SDIM);
    int4 a = q[0];
    int4 b = q[1];
    const __half2* ha = reinterpret_cast<const __half2*>(&a);
    const __half2* hb = reinterpret_cast<const __half2*>(&b);
    #pragma unroll
    for (int d = 0; d < 4; ++d) {
        float2 f = __half22float2(ha[d]);
        S[2 * d]     += w * f.x;
        S[2 * d + 1] += w * f.y;
    }
    #pragma unroll
    for (int d = 0; d < 4; ++d) {
        float2 f = __half22float2(hb[d]);
        S[8 + 2 * d]     += w * f.x;
        S[8 + 2 * d + 1] += w * f.y;
    }
}
__device__ __forceinline__ void ntload16(const __half* p, float* o) {
    intx4 a = __builtin_nontemporal_load(reinterpret_cast<const intx4*>(p));
    intx4 b = __builtin_nontemporal_load(reinterpret_cast<const intx4*>(p) + 1);
    union { intx4 v; __half2 h[4]; } ua, ub;
    ua.v = a; ub.v = b;
    #pragma unroll
    for (int d = 0; d < 4; ++d) {
        float2 f = __half22float2(ua.h[d]);
        o[2 * d]     = f.x;
        o[2 * d + 1] = f.y;
    }
    #pragma unroll
    for (int d = 0; d < 4; ++d) {
        float2 f = __half22float2(ub.h[d]);
        o[8 + 2 * d]     = f.x;
        o[8 + 2 * d + 1] = f.y;
    }
}
__device__ __forceinline__ void store16(__half* p, const float* v) {
    int4 r0, r1;
    __half2* h0 = reinterpret_cast<__half2*>(&r0);
    __half2* h1 = reinterpret_cast<__half2*>(&r1);
    #pragma unroll
    for (int d = 0; d < 4; ++d) h0[d] = __floats2half2_rn(v[2 * d], v[2 * d + 1]);
    #pragma unroll
    for (int d = 0; d < 4; ++d) h1[d] = __floats2half2_rn(v[8 + 2 * d], v[8 + 2 * d + 1]);
    reinterpret_cast<int4*>(p)[0] = r0;
    reinterpret_cast<int4*>(p)[1] = r1;
}
__device__ __forceinline__ void ntstore16(__half* p, const float* v) {
    union { intx4 v; __half2 h[4]; } r0, r1;
    #pragma unroll
    for (int d = 0; d < 4; ++d) r0.h[d] = __floats2half2_rn(v[2 * d], v[2 * d + 1]);
    #pragma unroll
    for (int d = 0; d < 4; ++d) r1.h[d] = __floats2half2_rn(v[8 + 2 * d], v[8 + 2 * d + 1]);
    __builtin_nontemporal_store(r0.v, reinterpret_cast<intx4*>(p));
    __builtin_nontemporal_store(r1.v, reinterpret_cast<intx4*>(p) + 1);
}

// ---------------------------------------------------------------------------
// Sliced propagate: slice = blockIdx&7 (-> XCD via round-robin dispatch),
// 1 lane per node, 16 dims per lane, 2-edge unroll.
//   MODE 0 (k=1): S = gather(xh_s);  T1_s = S
//   MODE 1 (k=2..4): S = gather(Tp1_s); Tc_s = 2S - Tp2_s
//   MODE 2 (k=5): S = gather(T4_s); T5 = 2S - T3_s;
//                 o = c0*x+..+c5*T5; o = o*sc+bi; write o (fp16, over xh);
//                 ssqp[s][n] = sum(o^2)
// Gather loads CACHED (slice stays L2-resident); streams NT.
// ---------------------------------------------------------------------------
template <int MODE>
__global__ __launch_bounds__(256)
void prop_slice(const __half* __restrict__ Tsrc,
                const __half* __restrict__ Tp2,
                const __half* xh,                 // MODE2 (aliases o_out)
                const __half* __restrict__ T1b,   // MODE2
                const __half* __restrict__ T2b,   // MODE2
                const int* __restrict__ rowptr,
                const int* __restrict__ epk,
                const float* __restrict__ cheb,
                const float* __restrict__ gscale,
                const float* __restrict__ gbias,
                __half* Tc,                       // output slice buffer (o for MODE2)
                float* __restrict__ ssqp) {
    int slice = blockIdx.x & 7;
    int n = (blockIdx.x >> 3) * 256 + threadIdx.x;
    if (n >= N_NODES) return;
    const __half* sb = Tsrc + (size_t)slice * SS;
    int beg = rowptr[n];
    int end = rowptr[n + 1];

    float S[16];
    #pragma unroll
    for (int q = 0; q < 16; ++q) S[q] = 0.0f;

    int j = beg;
    for (; j + 1 < end; j += 2) {
        int p0 = __builtin_nontemporal_load(epk + j);
        int p1 = __builtin_nontemporal_load(epk + j + 1);
        gfma(sb, p0, S);
        gfma(sb, p1, S);
    }
    if (j < end) {
        int p0 = __builtin_nontemporal_load(epk + j);
        gfma(sb, p0, S);
    }

    size_t off = (size_t)slice * SS + (size_t)n * SDIM;

    if (MODE == 0) {
        store16(Tc + off, S);                          // cached: next step's gather
    } else if (MODE == 1) {
        float p[16];
        ntload16(Tp2 + off, p);                        // last use of T_{k-2}
        float t[16];
        #pragma unroll
        for (int q = 0; q < 16; ++q) t[q] = 2.0f * S[q] - p[q];
        store16(Tc + off, t);                          // cached
    } else {
        float t3[16], xr[16], t1[16], t2[16], t4[16];
        ntload16(Tp2 + off, t3);
        ntload16(xh + off, xr);
        ntload16(T1b + off, t1);
        ntload16(T2b + off, t2);
        ntload16(Tsrc + off, t4);
        int g = slice >> 1;                            // 32 dims per group
        float c0 = cheb[g * KP1 + 0], c1 = cheb[g * KP1 + 1], c2 = cheb[g * KP1 + 2];
        float c3 = cheb[g * KP1 + 3], c4 = cheb[g * KP1 + 4], c5 = cheb[g * KP1 + 5];
        float sc = gscale[g];
        float bi = gbias[g];
        float o[16];
        float ss = 0.0f;
        #pragma unroll
        for (int q = 0; q < 16; ++q) {
            float t5 = 2.0f * S[q] - t3[q];
            float v = c0 * xr[q] + c1 * t1[q] + c2 * t2[q] + c3 * t3[q]
                    + c4 * t4[q] + c5 * t5;
            v = v * sc + bi;
            o[q] = v;
            ss += v * v;
        }
        ntstore16(Tc + off, o);                        // o, read once by norm
        ssqp[slice * N_NODES + n] = ss;
    }
}

// ---------------------------------------------------------------------------
// final: reduce ssq across slices, RMSNorm affine + SiLU, write out row-major
// 16 lanes per node; lane l covers dims [l*8, l*8+8) = slice l>>1, half l&1
// ---------------------------------------------------------------------------
__global__ __launch_bounds__(256)
void norm_kernel(const __half* __restrict__ oh,
                 const float* __restrict__ ssqp,
                 const float* __restrict__ rmsw,
                 float* __restrict__ out) {
    int t = blockIdx.x * 256 + threadIdx.x;
    int n = t >> 4;
    int l = t & 15;
    if (n >= N_NODES) return;
    int s = l >> 1, h = l & 1;
    size_t off = (size_t)s * SS + (size_t)n * SDIM + h * 8;
    int4 r = *reinterpret_cast<const int4*>(oh + off);
    const __half2* hh = reinterpret_cast<const __half2*>(&r);
    float o[8];
    #pragma unroll
    for (int d = 0; d < 4; ++d) {
        float2 f = __half22float2(hh[d]);
        o[2 * d]     = f.x;
        o[2 * d + 1] = f.y;
    }
    float ss = ssqp[s * N_NODES + n];
    // lanes l and l^1 hold the same slice partial; masks 2,4,8 visit each slice once
    ss += __shfl_xor(ss, 2, 64);
    ss += __shfl_xor(ss, 4, 64);
    ss += __shfl_xor(ss, 8, 64);
    float rr = rsqrtf(ss * (1.0f / HDIM) + RMS_EPS);
    int dbase = l * 8;
    float4 wa = *reinterpret_cast<const float4*>(rmsw + dbase);
    float4 wb = *reinterpret_cast<const float4*>(rmsw + dbase + 4);
    float wv[8] = {wa.x, wa.y, wa.z, wa.w, wb.x, wb.y, wb.z, wb.w};
    float res[8];
    #pragma unroll
    for (int q = 0; q < 8; ++q) {
        float a = o[q] * rr * wv[q];
        res[q] = a / (1.0f + expf(-a));
    }
    float4 ra = {res[0], res[1], res[2], res[3]};
    float4 rb = {res[4], res[5], res[6], res[7]};
    float* op = out + (size_t)n * HDIM + dbase;
    *reinterpret_cast<float4*>(op) = ra;
    *reinterpret_cast<float4*>(op + 4) = rb;
}

// ---------------------------------------------------------------------------
extern "C" void kernel_launch(void* const* d_in, const int* in_sizes, int n_in,
                              void* d_out, int out_size, void* d_ws, size_t ws_size,
                              hipStream_t stream) {
    const float* x      = (const float*)d_in[0];
    const float* ew     = (const float*)d_in[1];
    const float* cheb   = (const float*)d_in[2];
    const float* gscale = (const float*)d_in[3];
    const float* gbias  = (const float*)d_in[4];
    const float* rmsw   = (const float*)d_in[5];
    const int*   eidx   = (const int*)d_in[6];
    const int*   src    = eidx;               // edge_index[0]
    const int*   dst    = eidx + N_EDGES;     // edge_index[1]
    float* out = (float*)d_out;

    // workspace: 5 slice-major fp16 buffers (xh doubles as o), then indices
    const size_t NH = (size_t)N_NODES * HDIM;   // == 8*SS
    __half* xh = (__half*)d_ws;                 // 25.6 MB (o overwrites it in k=5)
    __half* T1 = xh + NH;
    __half* T2 = T1 + NH;
    __half* T3 = T2 + NH;
    __half* T4 = T3 + NH;
    int*   epk      = (int*)(T4 + NH);          // E * 4 B
    float* ssqp     = (float*)(epk + N_EDGES);  // 8 * N floats
    int*   deg      = (int*)(ssqp + NSLICE * N_NODES);
    int*   inc      = deg + N_NODES;
    int*   rowptr   = inc + N_NODES;            // N+1
    int*   cursor   = rowptr + N_NODES + 1;
    int*   blockSums= cursor + N_NODES;         // 512

    const int TB = 256;
    const int edge_blocks = (N_EDGES + TB - 1) / TB;        // 1563
    const int lane_blocks = (N_NODES * 16 + TB - 1) / TB;   // 6250
    const int prop_blocks = NSLICE * ((N_NODES + TB - 1) / TB);  // 8*391

    // ---- x -> slice-major fp16 + CSR build ----
    x2h_slice_kernel<<<lane_blocks, TB, 0, stream>>>(x, xh);
    hipMemsetAsync(deg, 0, N_NODES * sizeof(int), stream);
    hist_kernel<<<edge_blocks, TB, 0, stream>>>(dst, deg);
    scan_local_kernel<<<N_SCAN_BLOCKS, SCAN_B, 0, stream>>>(deg, inc, blockSums);
    scan_blocks_kernel<<<1, 512, 0, stream>>>(blockSums);
    finalize_kernel<<<N_SCAN_BLOCKS, SCAN_B, 0, stream>>>(deg, inc, blockSums, rowptr, cursor);
    fill_kernel<<<edge_blocks, TB, 0, stream>>>(src, dst, ew, cursor, epk);

    // ---- sliced Chebyshev propagates ----
    // k=1: T1 = prop(xh)
    prop_slice<0><<<prop_blocks, TB, 0, stream>>>(xh, nullptr, nullptr, nullptr, nullptr,
                                                  rowptr, epk, cheb, gscale, gbias,
                                                  T1, nullptr);
    // k=2: T2 = 2*prop(T1) - xh
    prop_slice<1><<<prop_blocks, TB, 0, stream>>>(T1, xh, nullptr, nullptr, nullptr,
                                                  rowptr, epk, cheb, gscale, gbias,
                                                  T2, nullptr);
    // k=3: T3 = 2*prop(T2) - T1
    prop_slice<1><<<prop_blocks, TB, 0, stream>>>(T2, T1, nullptr, nullptr, nullptr,
                                                  rowptr, epk, cheb, gscale, gbias,
                                                  T3, nullptr);
    // k=4: T4 = 2*prop(T3) - T2
    prop_slice<1><<<prop_blocks, TB, 0, stream>>>(T3, T2, nullptr, nullptr, nullptr,
                                                  rowptr, epk, cheb, gscale, gbias,
                                                  T4, nullptr);
    // k=5: o = gaffine(sum c_k T_k) into xh; partial ssq
    prop_slice<2><<<prop_blocks, TB, 0, stream>>>(T4, T3, xh, T1, T2,
                                                  rowptr, epk, cheb, gscale, gbias,
                                                  xh, ssqp);
    // final: RMSNorm + SiLU
    norm_kernel<<<lane_blocks, TB, 0, stream>>>(xh, ssqp, rmsw, out);
}

// Round 10
// 210.721 us; speedup vs baseline: 1.6466x; 1.6466x over previous
//
#include <hip/hip_runtime.h>
#include <hip/hip_fp16.h>
#include <math.h>

#define N_NODES 100000
#define N_EDGES 400000
#define HDIM    128
#define KP1     6      // K+1 coefficients per group
#define RMS_EPS 1.1920929e-07f

#define SCAN_B  256
#define N_SCAN_BLOCKS ((N_NODES + SCAN_B - 1) / SCAN_B)   // 391

// native clang vector type for nontemporal builtins
typedef int intx4 __attribute__((ext_vector_type(4)));

// ---------------------------------------------------------------------------
// x -> fp16 copy (vectorized, 8 elems/thread)
// ---------------------------------------------------------------------------
__global__ __launch_bounds__(256)
void x2h_kernel(const float* __restrict__ x, __half* __restrict__ xh) {
    size_t i = (size_t)blockIdx.x * blockDim.x + threadIdx.x;
    const size_t total = (size_t)N_NODES * HDIM / 8;
    if (i >= total) return;
    const float4 a = reinterpret_cast<const float4*>(x)[2 * i];
    const float4 b = reinterpret_cast<const float4*>(x)[2 * i + 1];
    int4 r;
    __half2* h = reinterpret_cast<__half2*>(&r);
    h[0] = __floats2half2_rn(a.x, a.y);
    h[1] = __floats2half2_rn(a.z, a.w);
    h[2] = __floats2half2_rn(b.x, b.y);
    h[3] = __floats2half2_rn(b.z, b.w);
    reinterpret_cast<int4*>(xh)[i] = r;
}

// ---------------------------------------------------------------------------
// CSR build step 1: histogram of destination degrees
// ---------------------------------------------------------------------------
__global__ void hist_kernel(const int* __restrict__ dst, int* __restrict__ deg) {
    int e = blockIdx.x * blockDim.x + threadIdx.x;
    if (e >= N_EDGES) return;
    atomicAdd(&deg[dst[e]], 1);
}

// ---------------------------------------------------------------------------
// CSR build step 2a: per-block inclusive scan of deg
// ---------------------------------------------------------------------------
__global__ void scan_local_kernel(const int* __restrict__ deg,
                                  int* __restrict__ inc,
                                  int* __restrict__ blockSums) {
    __shared__ int lds[SCAN_B];
    int i = blockIdx.x * SCAN_B + threadIdx.x;
    int v = (i < N_NODES) ? deg[i] : 0;
    lds[threadIdx.x] = v;
    __syncthreads();
    #pragma unroll
    for (int off = 1; off < SCAN_B; off <<= 1) {
        int t = (threadIdx.x >= off) ? lds[threadIdx.x - off] : 0;
        __syncthreads();
        lds[threadIdx.x] += t;
        __syncthreads();
    }
    if (i < N_NODES) inc[i] = lds[threadIdx.x];
    if (threadIdx.x == SCAN_B - 1) blockSums[blockIdx.x] = lds[SCAN_B - 1];
}

// ---------------------------------------------------------------------------
// CSR build step 2b: exclusive scan of the 391 block sums (single block)
// ---------------------------------------------------------------------------
__global__ void scan_blocks_kernel(int* __restrict__ blockSums) {
    __shared__ int lds[512];
    int v = (threadIdx.x < N_SCAN_BLOCKS) ? blockSums[threadIdx.x] : 0;
    lds[threadIdx.x] = v;
    __syncthreads();
    #pragma unroll
    for (int off = 1; off < 512; off <<= 1) {
        int t = ((int)threadIdx.x >= off) ? lds[threadIdx.x - off] : 0;
        __syncthreads();
        lds[threadIdx.x] += t;
        __syncthreads();
    }
    if (threadIdx.x < N_SCAN_BLOCKS)
        blockSums[threadIdx.x] = (threadIdx.x == 0) ? 0 : lds[threadIdx.x - 1];
}

// ---------------------------------------------------------------------------
// CSR build step 2c: rowptr (exclusive) + cursor copy
// ---------------------------------------------------------------------------
__global__ void finalize_kernel(const int* __restrict__ deg,
                                const int* __restrict__ inc,
                                const int* __restrict__ blockSums,
                                int* __restrict__ rowptr,
                                int* __restrict__ cursor) {
    int i = blockIdx.x * SCAN_B + threadIdx.x;
    if (i >= N_NODES) return;
    int ex = inc[i] - deg[i] + blockSums[i >> 8];
    rowptr[i] = ex;
    cursor[i] = ex;
    if (i == 0) rowptr[N_NODES] = N_EDGES;
}

// ---------------------------------------------------------------------------
// CSR build step 3: fill packed (src_row_offset, weight) per slot
// ---------------------------------------------------------------------------
__global__ void fill_kernel(const int* __restrict__ src,
                            const int* __restrict__ dst,
                            const float* __restrict__ ew,
                            int* __restrict__ cursor,
                            int2* __restrict__ epack) {
    int e = blockIdx.x * blockDim.x + threadIdx.x;
    if (e >= N_EDGES) return;
    int d = dst[e];
    int pos = atomicAdd(&cursor[d], 1);
    int2 p;
    p.x = src[e] * HDIM;                 // element offset of source row
    p.y = __float_as_int(ew[e]);
    epack[pos] = p;
}

// ---------------------------------------------------------------------------
// helpers: 8-dim fp16 fragments per lane
//   gather loads: CACHED (the only stream with reuse)
//   row streams (Tp2, epilogue reads): NON-TEMPORAL loads
//   Tc / out writes: NON-TEMPORAL stores
// ---------------------------------------------------------------------------
__device__ __forceinline__ void fma8_h(const __half* __restrict__ p, float w, float* S) {
    int4 r = *reinterpret_cast<const int4*>(p);       // cached gather
    const __half2* h = reinterpret_cast<const __half2*>(&r);
    #pragma unroll
    for (int q = 0; q < 4; ++q) {
        float2 f = __half22float2(h[q]);
        S[2 * q + 0] += w * f.x;
        S[2 * q + 1] += w * f.y;
    }
}
__device__ __forceinline__ void ntload8_h(const __half* __restrict__ p, float* o) {
    intx4 r = __builtin_nontemporal_load(reinterpret_cast<const intx4*>(p));
    union { intx4 v; __half2 h[4]; } u;
    u.v = r;
    #pragma unroll
    for (int q = 0; q < 4; ++q) {
        float2 f = __half22float2(u.h[q]);
        o[2 * q + 0] = f.x;
        o[2 * q + 1] = f.y;
    }
}
__device__ __forceinline__ void ntstore8_h(__half* __restrict__ p, const float* v) {
    union { intx4 v; __half2 h[4]; } r;
    #pragma unroll
    for (int q = 0; q < 4; ++q)
        r.h[q] = __floats2half2_rn(v[2 * q + 0], v[2 * q + 1]);
    __builtin_nontemporal_store(r.v, reinterpret_cast<intx4*>(p));
}

// ---------------------------------------------------------------------------
// Fused propagate: 16 lanes per node (8 dims/lane), 4 nodes per wave,
// 16 nodes per 256-thread block; 4x unrolled fp16 gathers (16B/lane).
//   MODE 0 (k=1):     S = gather(xh);  write T1 = S
//   MODE 1 (k=2,3,4): S = gather(Tp1); write Tc = 2S - Tp2
//   MODE 2 (k=5):     S = gather(T4);  T5 = 2S - T3;
//                     o = c0*xh + c1*T1 + ... + c5*T5;
//                     group affine -> RMSNorm -> SiLU -> out (f32)
// ---------------------------------------------------------------------------
template <int MODE>
__global__ __launch_bounds__(256)
void prop_kernel(const __half* __restrict__ Tp1h,   // gather source
                 const __half* __restrict__ Tp2h,
                 const __half* __restrict__ xh,     // MODE 2 only
                 const int* __restrict__ rowptr,
                 const int2* __restrict__ epack,
                 const float* __restrict__ cheb,
                 __half* __restrict__ Tch,
                 const __half* __restrict__ T1h,    // MODE 2 only
                 const __half* __restrict__ T2h,    // MODE 2 only
                 float* __restrict__ out,
                 const float* __restrict__ gscale,
                 const float* __restrict__ gbias,
                 const float* __restrict__ rmsw) {
    int grp = threadIdx.x >> 4;                  // 16-lane group id within block
    int sub = threadIdx.x & 15;                  // lane within group
    int row = blockIdx.x * 16 + grp;
    if (row >= N_NODES) return;

    int beg = rowptr[row];
    int end = rowptr[row + 1];
    int d8 = sub * 8;                            // dim offset of this lane

    float S[8] = {0, 0, 0, 0, 0, 0, 0, 0};
    int j = beg;
    for (; j + 3 < end; j += 4) {
        int2 e0 = epack[j], e1 = epack[j + 1], e2 = epack[j + 2], e3 = epack[j + 3];
        float w0 = __int_as_float(e0.y), w1 = __int_as_float(e1.y);
        float w2 = __int_as_float(e2.y), w3 = __int_as_float(e3.y);
        fma8_h(Tp1h + e0.x + d8, w0, S);
        fma8_h(Tp1h + e1.x + d8, w1, S);
        fma8_h(Tp1h + e2.x + d8, w2, S);
        fma8_h(Tp1h + e3.x + d8, w3, S);
    }
    for (; j < end; ++j) {
        int2 e0 = epack[j];
        float w = __int_as_float(e0.y);
        fma8_h(Tp1h + e0.x + d8, w, S);
    }

    size_t off = (size_t)row * HDIM + d8;
    int g = sub >> 2;                            // group index (32 dims per group)

    if (MODE == 0) {
        ntstore8_h(Tch + off, S);
    } else if (MODE == 1) {
        float p[8];
        ntload8_h(Tp2h + off, p);
        float t[8];
        #pragma unroll
        for (int q = 0; q < 8; ++q) t[q] = 2.0f * S[q] - p[q];
        ntstore8_h(Tch + off, t);
    } else {
        // final: full polynomial sum + epilogue
        float t3[8], t1[8], t2[8], t4[8], xr[8];
        ntload8_h(Tp2h + off, t3);       // T3 row
        ntload8_h(T1h + off, t1);
        ntload8_h(T2h + off, t2);
        ntload8_h(Tp1h + off, t4);       // T4 row (gather source this step)
        ntload8_h(xh + off, xr);

        float c0 = cheb[g * KP1 + 0], c1 = cheb[g * KP1 + 1], c2 = cheb[g * KP1 + 2];
        float c3 = cheb[g * KP1 + 3], c4 = cheb[g * KP1 + 4], c5 = cheb[g * KP1 + 5];
        float sc = gscale[g];
        float bi = gbias[g];

        float o[8];
        float ss = 0.0f;
        #pragma unroll
        for (int q = 0; q < 8; ++q) {
            float t5 = 2.0f * S[q] - t3[q];
            float v = c0 * xr[q] + c1 * t1[q] + c2 * t2[q] + c3 * t3[q]
                    + c4 * t4[q] + c5 * t5;
            v = v * sc + bi;
            o[q] = v;
            ss += v * v;
        }
        // reduce over the 16 lanes of this group (masks 1,2,4,8 stay in-group)
        #pragma unroll
        for (int m = 1; m < 16; m <<= 1)
            ss += __shfl_xor(ss, m, 64);
        float r = rsqrtf(ss * (1.0f / HDIM) + RMS_EPS);

        float4 wa = *reinterpret_cast<const float4*>(rmsw + d8);
        float4 wb = *reinterpret_cast<const float4*>(rmsw + d8 + 4);
        float wv[8] = {wa.x, wa.y, wa.z, wa.w, wb.x, wb.y, wb.z, wb.w};
        float res[8];
        #pragma unroll
        for (int q = 0; q < 8; ++q) {
            float a = o[q] * r * wv[q];
            res[q] = a / (1.0f + expf(-a));
        }
        typedef float floatx4 __attribute__((ext_vector_type(4)));
        floatx4 ra = {res[0], res[1], res[2], res[3]};
        floatx4 rb = {res[4], res[5], res[6], res[7]};
        __builtin_nontemporal_store(ra, reinterpret_cast<floatx4*>(out + off));
        __builtin_nontemporal_store(rb, reinterpret_cast<floatx4*>(out + off + 4));
    }
}

// ---------------------------------------------------------------------------
extern "C" void kernel_launch(void* const* d_in, const int* in_sizes, int n_in,
                              void* d_out, int out_size, void* d_ws, size_t ws_size,
                              hipStream_t stream) {
    const float* x      = (const float*)d_in[0];
    const float* ew     = (const float*)d_in[1];
    const float* cheb   = (const float*)d_in[2];
    const float* gscale = (const float*)d_in[3];
    const float* gbias  = (const float*)d_in[4];
    const float* rmsw   = (const float*)d_in[5];
    const int*   eidx   = (const int*)d_in[6];
    const int*   src    = eidx;               // edge_index[0]
    const int*   dst    = eidx + N_EDGES;     // edge_index[1]
    float* out = (float*)d_out;

    // workspace layout
    const size_t NH = (size_t)N_NODES * HDIM;
    __half* xh  = (__half*)d_ws;
    __half* T1  = xh + NH;
    __half* T2  = T1 + NH;
    __half* T3  = T2 + NH;
    __half* T4  = T3 + NH;
    int2*  epack    = (int2*)(T4 + NH);           // E entries (8B aligned)
    int*   deg      = (int*)(epack + N_EDGES);
    int*   inc      = deg + N_NODES;
    int*   rowptr   = inc + N_NODES;              // N+1
    int*   cursor   = rowptr + N_NODES + 1;
    int*   blockSums= cursor + N_NODES;           // 512

    const int TB = 256;
    const int edge_blocks = (N_EDGES + TB - 1) / TB;    // 1563
    const int conv_blocks = (int)((NH / 8 + TB - 1) / TB); // 6250
    const int prop_blocks = (N_NODES + 15) / 16;        // 6250

    // ---- x -> fp16 + CSR build (by destination) ----
    x2h_kernel<<<conv_blocks, TB, 0, stream>>>(x, xh);
    hipMemsetAsync(deg, 0, N_NODES * sizeof(int), stream);
    hist_kernel<<<edge_blocks, TB, 0, stream>>>(dst, deg);
    scan_local_kernel<<<N_SCAN_BLOCKS, SCAN_B, 0, stream>>>(deg, inc, blockSums);
    scan_blocks_kernel<<<1, 512, 0, stream>>>(blockSums);
    finalize_kernel<<<N_SCAN_BLOCKS, SCAN_B, 0, stream>>>(deg, inc, blockSums, rowptr, cursor);
    fill_kernel<<<edge_blocks, TB, 0, stream>>>(src, dst, ew, cursor, epack);

    // ---- fused Chebyshev propagates (all fp16) ----
    // k=1: T1 = prop(xh)
    prop_kernel<0><<<prop_blocks, TB, 0, stream>>>(xh, nullptr, nullptr, rowptr, epack,
                                                   cheb, T1, nullptr, nullptr,
                                                   out, gscale, gbias, rmsw);
    // k=2: T2 = 2*prop(T1) - xh
    prop_kernel<1><<<prop_blocks, TB, 0, stream>>>(T1, xh, nullptr, rowptr, epack,
                                                   cheb, T2, nullptr, nullptr,
                                                   out, gscale, gbias, rmsw);
    // k=3: T3 = 2*prop(T2) - T1
    prop_kernel<1><<<prop_blocks, TB, 0, stream>>>(T2, T1, nullptr, rowptr, epack,
                                                   cheb, T3, nullptr, nullptr,
                                                   out, gscale, gbias, rmsw);
    // k=4: T4 = 2*prop(T3) - T2
    prop_kernel<1><<<prop_blocks, TB, 0, stream>>>(T3, T2, nullptr, rowptr, epack,
                                                   cheb, T4, nullptr, nullptr,
                                                   out, gscale, gbias, rmsw);
    // k=5: T5 = 2*prop(T4) - T3; out = silu(rms(gaffine(sum c_k T_k)))
    prop_kernel<2><<<prop_blocks, TB, 0, stream>>>(T4, T3, xh, rowptr, epack,
                                                   cheb, nullptr, T1, T2,
                                                   out, gscale, gbias, rmsw);
}

// Round 11
// 210.570 us; speedup vs baseline: 1.6477x; 1.0007x over previous
//
#include <hip/hip_runtime.h>
#include <hip/hip_fp16.h>
#include <math.h>

#define N_NODES 100000
#define N_EDGES 400000
#define HDIM    128
#define KP1     6      // K+1 coefficients per group
#define RMS_EPS 1.1920929e-07f

#define SCAN_B  256
#define N_SCAN_BLOCKS ((N_NODES + SCAN_B - 1) / SCAN_B)   // 391

// ---------------------------------------------------------------------------
// x -> fp16 copy (vectorized, 8 elems/thread)
// ---------------------------------------------------------------------------
__global__ __launch_bounds__(256)
void x2h_kernel(const float* __restrict__ x, __half* __restrict__ xh) {
    size_t i = (size_t)blockIdx.x * blockDim.x + threadIdx.x;
    const size_t total = (size_t)N_NODES * HDIM / 8;
    if (i >= total) return;
    const float4 a = reinterpret_cast<const float4*>(x)[2 * i];
    const float4 b = reinterpret_cast<const float4*>(x)[2 * i + 1];
    int4 r;
    __half2* h = reinterpret_cast<__half2*>(&r);
    h[0] = __floats2half2_rn(a.x, a.y);
    h[1] = __floats2half2_rn(a.z, a.w);
    h[2] = __floats2half2_rn(b.x, b.y);
    h[3] = __floats2half2_rn(b.z, b.w);
    reinterpret_cast<int4*>(xh)[i] = r;
}

// ---------------------------------------------------------------------------
// CSR build step 1: histogram of destination degrees
// ---------------------------------------------------------------------------
__global__ void hist_kernel(const int* __restrict__ dst, int* __restrict__ deg) {
    int e = blockIdx.x * blockDim.x + threadIdx.x;
    if (e >= N_EDGES) return;
    atomicAdd(&deg[dst[e]], 1);
}

// ---------------------------------------------------------------------------
// CSR build step 2a: per-block inclusive scan of deg
// ---------------------------------------------------------------------------
__global__ void scan_local_kernel(const int* __restrict__ deg,
                                  int* __restrict__ inc,
                                  int* __restrict__ blockSums) {
    __shared__ int lds[SCAN_B];
    int i = blockIdx.x * SCAN_B + threadIdx.x;
    int v = (i < N_NODES) ? deg[i] : 0;
    lds[threadIdx.x] = v;
    __syncthreads();
    #pragma unroll
    for (int off = 1; off < SCAN_B; off <<= 1) {
        int t = (threadIdx.x >= off) ? lds[threadIdx.x - off] : 0;
        __syncthreads();
        lds[threadIdx.x] += t;
        __syncthreads();
    }
    if (i < N_NODES) inc[i] = lds[threadIdx.x];
    if (threadIdx.x == SCAN_B - 1) blockSums[blockIdx.x] = lds[SCAN_B - 1];
}

// ---------------------------------------------------------------------------
// CSR build step 2b: exclusive scan of the 391 block sums (single block)
// ---------------------------------------------------------------------------
__global__ void scan_blocks_kernel(int* __restrict__ blockSums) {
    __shared__ int lds[512];
    int v = (threadIdx.x < N_SCAN_BLOCKS) ? blockSums[threadIdx.x] : 0;
    lds[threadIdx.x] = v;
    __syncthreads();
    #pragma unroll
    for (int off = 1; off < 512; off <<= 1) {
        int t = ((int)threadIdx.x >= off) ? lds[threadIdx.x - off] : 0;
        __syncthreads();
        lds[threadIdx.x] += t;
        __syncthreads();
    }
    if (threadIdx.x < N_SCAN_BLOCKS)
        blockSums[threadIdx.x] = (threadIdx.x == 0) ? 0 : lds[threadIdx.x - 1];
}

// ---------------------------------------------------------------------------
// CSR build step 2c: rowptr (exclusive) + cursor copy
// ---------------------------------------------------------------------------
__global__ void finalize_kernel(const int* __restrict__ deg,
                                const int* __restrict__ inc,
                                const int* __restrict__ blockSums,
                                int* __restrict__ rowptr,
                                int* __restrict__ cursor) {
    int i = blockIdx.x * SCAN_B + threadIdx.x;
    if (i >= N_NODES) return;
    int ex = inc[i] - deg[i] + blockSums[i >> 8];
    rowptr[i] = ex;
    cursor[i] = ex;
    if (i == 0) rowptr[N_NODES] = N_EDGES;
}

// ---------------------------------------------------------------------------
// CSR build step 3: fill packed (src_row_offset, weight) per slot
// ---------------------------------------------------------------------------
__global__ void fill_kernel(const int* __restrict__ src,
                            const int* __restrict__ dst,
                            const float* __restrict__ ew,
                            int* __restrict__ cursor,
                            int2* __restrict__ epack) {
    int e = blockIdx.x * blockDim.x + threadIdx.x;
    if (e >= N_EDGES) return;
    int d = dst[e];
    int pos = atomicAdd(&cursor[d], 1);
    int2 p;
    p.x = src[e] * HDIM;                 // element offset of source row
    p.y = __float_as_int(ew[e]);
    epack[pos] = p;
}

// ---------------------------------------------------------------------------
// helpers: 8-dim fp16 fragments per lane (all cached loads/stores — r8 best)
// ---------------------------------------------------------------------------
__device__ __forceinline__ void fma8_h(const __half* __restrict__ p, float w, float* S) {
    int4 r = *reinterpret_cast<const int4*>(p);       // 8 halves
    const __half2* h = reinterpret_cast<const __half2*>(&r);
    #pragma unroll
    for (int q = 0; q < 4; ++q) {
        float2 f = __half22float2(h[q]);
        S[2 * q + 0] += w * f.x;
        S[2 * q + 1] += w * f.y;
    }
}
__device__ __forceinline__ void load8_h(const __half* __restrict__ p, float* o) {
    int4 r = *reinterpret_cast<const int4*>(p);
    const __half2* h = reinterpret_cast<const __half2*>(&r);
    #pragma unroll
    for (int q = 0; q < 4; ++q) {
        float2 f = __half22float2(h[q]);
        o[2 * q + 0] = f.x;
        o[2 * q + 1] = f.y;
    }
}
__device__ __forceinline__ void store8_h(__half* __restrict__ p, const float* v) {
    int4 r;
    __half2* h = reinterpret_cast<__half2*>(&r);
    #pragma unroll
    for (int q = 0; q < 4; ++q)
        h[q] = __floats2half2_rn(v[2 * q + 0], v[2 * q + 1]);
    *reinterpret_cast<int4*>(p) = r;
}

// ---------------------------------------------------------------------------
// Fused propagate: 16 lanes per node (8 dims/lane), 4 nodes per wave,
// 16 nodes per 256-thread block; 4x unrolled fp16 gathers (16B/lane).
// Row-stream loads (Tp2 / epilogue inputs) are issued BEFORE the gather loop
// so their latency hides under the gather requests.
//   MODE 0 (k=1):     S = gather(xh);  write T1 = S
//   MODE 1 (k=2,3,4): S = gather(Tp1); write Tc = 2S - Tp2
//   MODE 2 (k=5):     S = gather(T4);  T5 = 2S - T3;
//                     o = c0*xh + c1*T1 + ... + c5*T5;
//                     group affine -> RMSNorm -> SiLU -> out (f32)
// ---------------------------------------------------------------------------
template <int MODE>
__global__ __launch_bounds__(256)
void prop_kernel(const __half* __restrict__ Tp1h,   // gather source
                 const __half* __restrict__ Tp2h,
                 const __half* __restrict__ xh,     // MODE 2 only
                 const int* __restrict__ rowptr,
                 const int2* __restrict__ epack,
                 const float* __restrict__ cheb,
                 __half* __restrict__ Tch,
                 const __half* __restrict__ T1h,    // MODE 2 only
                 const __half* __restrict__ T2h,    // MODE 2 only
                 float* __restrict__ out,
                 const float* __restrict__ gscale,
                 const float* __restrict__ gbias,
                 const float* __restrict__ rmsw) {
    int grp = threadIdx.x >> 4;                  // 16-lane group id within block
    int sub = threadIdx.x & 15;                  // lane within group
    int row = blockIdx.x * 16 + grp;
    if (row >= N_NODES) return;

    int beg = rowptr[row];
    int end = rowptr[row + 1];
    int d8 = sub * 8;                            // dim offset of this lane
    size_t off = (size_t)row * HDIM + d8;

    // ---- issue independent row-stream loads early (overlap with gathers) ----
    float p2[8];                                 // MODE 1/2: Tp2 row
    float t1[8], t2[8], t4[8], xr[8];            // MODE 2 extras
    if (MODE == 1 || MODE == 2) load8_h(Tp2h + off, p2);
    if (MODE == 2) {
        load8_h(T1h + off, t1);
        load8_h(T2h + off, t2);
        load8_h(Tp1h + off, t4);                 // T4 row (gather source buffer)
        load8_h(xh + off, xr);
    }

    float S[8] = {0, 0, 0, 0, 0, 0, 0, 0};
    int j = beg;
    for (; j + 3 < end; j += 4) {
        int2 e0 = epack[j], e1 = epack[j + 1], e2 = epack[j + 2], e3 = epack[j + 3];
        float w0 = __int_as_float(e0.y), w1 = __int_as_float(e1.y);
        float w2 = __int_as_float(e2.y), w3 = __int_as_float(e3.y);
        fma8_h(Tp1h + e0.x + d8, w0, S);
        fma8_h(Tp1h + e1.x + d8, w1, S);
        fma8_h(Tp1h + e2.x + d8, w2, S);
        fma8_h(Tp1h + e3.x + d8, w3, S);
    }
    for (; j < end; ++j) {
        int2 e0 = epack[j];
        float w = __int_as_float(e0.y);
        fma8_h(Tp1h + e0.x + d8, w, S);
    }

    int g = sub >> 2;                            // group index (32 dims per group)

    if (MODE == 0) {
        store8_h(Tch + off, S);
    } else if (MODE == 1) {
        float t[8];
        #pragma unroll
        for (int q = 0; q < 8; ++q) t[q] = 2.0f * S[q] - p2[q];
        store8_h(Tch + off, t);
    } else {
        float c0 = cheb[g * KP1 + 0], c1 = cheb[g * KP1 + 1], c2 = cheb[g * KP1 + 2];
        float c3 = cheb[g * KP1 + 3], c4 = cheb[g * KP1 + 4], c5 = cheb[g * KP1 + 5];
        float sc = gscale[g];
        float bi = gbias[g];

        float o[8];
        float ss = 0.0f;
        #pragma unroll
        for (int q = 0; q < 8; ++q) {
            float t5 = 2.0f * S[q] - p2[q];      // p2 = T3 row
            float v = c0 * xr[q] + c1 * t1[q] + c2 * t2[q] + c3 * p2[q]
                    + c4 * t4[q] + c5 * t5;
            v = v * sc + bi;
            o[q] = v;
            ss += v * v;
        }
        // reduce over the 16 lanes of this group (masks 1,2,4,8 stay in-group)
        #pragma unroll
        for (int m = 1; m < 16; m <<= 1)
            ss += __shfl_xor(ss, m, 64);
        float r = rsqrtf(ss * (1.0f / HDIM) + RMS_EPS);

        float4 wa = *reinterpret_cast<const float4*>(rmsw + d8);
        float4 wb = *reinterpret_cast<const float4*>(rmsw + d8 + 4);
        float wv[8] = {wa.x, wa.y, wa.z, wa.w, wb.x, wb.y, wb.z, wb.w};
        float res[8];
        #pragma unroll
        for (int q = 0; q < 8; ++q) {
            float a = o[q] * r * wv[q];
            res[q] = a / (1.0f + expf(-a));
        }
        float4 ra = {res[0], res[1], res[2], res[3]};
        float4 rb = {res[4], res[5], res[6], res[7]};
        *reinterpret_cast<float4*>(out + off) = ra;
        *reinterpret_cast<float4*>(out + off + 4) = rb;
    }
}

// ---------------------------------------------------------------------------
extern "C" void kernel_launch(void* const* d_in, const int* in_sizes, int n_in,
                              void* d_out, int out_size, void* d_ws, size_t ws_size,
                              hipStream_t stream) {
    const float* x      = (const float*)d_in[0];
    const float* ew     = (const float*)d_in[1];
    const float* cheb   = (const float*)d_in[2];
    const float* gscale = (const float*)d_in[3];
    const float* gbias  = (const float*)d_in[4];
    const float* rmsw   = (const float*)d_in[5];
    const int*   eidx   = (const int*)d_in[6];
    const int*   src    = eidx;               // edge_index[0]
    const int*   dst    = eidx + N_EDGES;     // edge_index[1]
    float* out = (float*)d_out;

    // workspace layout
    const size_t NH = (size_t)N_NODES * HDIM;
    __half* xh  = (__half*)d_ws;
    __half* T1  = xh + NH;
    __half* T2  = T1 + NH;
    __half* T3  = T2 + NH;
    __half* T4  = T3 + NH;
    int2*  epack    = (int2*)(T4 + NH);           // E entries (8B aligned)
    int*   deg      = (int*)(epack + N_EDGES);
    int*   inc      = deg + N_NODES;
    int*   rowptr   = inc + N_NODES;              // N+1
    int*   cursor   = rowptr + N_NODES + 1;
    int*   blockSums= cursor + N_NODES;           // 512

    const int TB = 256;
    const int edge_blocks = (N_EDGES + TB - 1) / TB;    // 1563
    const int conv_blocks = (int)((NH / 8 + TB - 1) / TB); // 6250
    const int prop_blocks = (N_NODES + 15) / 16;        // 6250

    // ---- x -> fp16 + CSR build (by destination) ----
    x2h_kernel<<<conv_blocks, TB, 0, stream>>>(x, xh);
    hipMemsetAsync(deg, 0, N_NODES * sizeof(int), stream);
    hist_kernel<<<edge_blocks, TB, 0, stream>>>(dst, deg);
    scan_local_kernel<<<N_SCAN_BLOCKS, SCAN_B, 0, stream>>>(deg, inc, blockSums);
    scan_blocks_kernel<<<1, 512, 0, stream>>>(blockSums);
    finalize_kernel<<<N_SCAN_BLOCKS, SCAN_B, 0, stream>>>(deg, inc, blockSums, rowptr, cursor);
    fill_kernel<<<edge_blocks, TB, 0, stream>>>(src, dst, ew, cursor, epack);

    // ---- fused Chebyshev propagates (all fp16) ----
    // k=1: T1 = prop(xh)
    prop_kernel<0><<<prop_blocks, TB, 0, stream>>>(xh, nullptr, nullptr, rowptr, epack,
                                                   cheb, T1, nullptr, nullptr,
                                                   out, gscale, gbias, rmsw);
    // k=2: T2 = 2*prop(T1) - xh
    prop_kernel<1><<<prop_blocks, TB, 0, stream>>>(T1, xh, nullptr, rowptr, epack,
                                                   cheb, T2, nullptr, nullptr,
                                                   out, gscale, gbias, rmsw);
    // k=3: T3 = 2*prop(T2) - T1
    prop_kernel<1><<<prop_blocks, TB, 0, stream>>>(T2, T1, nullptr, rowptr, epack,
                                                   cheb, T3, nullptr, nullptr,
                                                   out, gscale, gbias, rmsw);
    // k=4: T4 = 2*prop(T3) - T2
    prop_kernel<1><<<prop_blocks, TB, 0, stream>>>(T3, T2, nullptr, rowptr, epack,
                                                   cheb, T4, nullptr, nullptr,
                                                   out, gscale, gbias, rmsw);
    // k=5: T5 = 2*prop(T4) - T3; out = silu(rms(gaffine(sum c_k T_k)))
    prop_kernel<2><<<prop_blocks, TB, 0, stream>>>(T4, T3, xh, rowptr, epack,
                                                   cheb, nullptr, T1, T2,
                                                   out, gscale, gbias, rmsw);
}

// Round 12
// 201.483 us; speedup vs baseline: 1.7220x; 1.0451x over previous
//
#include <hip/hip_runtime.h>
#include <hip/hip_fp16.h>
#include <math.h>

#define N_NODES 100000
#define N_EDGES 400000
#define HDIM    128
#define KP1     6      // K+1 coefficients per group
#define RMS_EPS 1.1920929e-07f

#define SCAN_B  256
#define N_SCAN_BLOCKS ((N_NODES + SCAN_B - 1) / SCAN_B)   // 391

// ---------------------------------------------------------------------------
// x -> fp16 copy (vectorized, 8 elems/thread)
// ---------------------------------------------------------------------------
__global__ __launch_bounds__(256)
void x2h_kernel(const float* __restrict__ x, __half* __restrict__ xh) {
    size_t i = (size_t)blockIdx.x * blockDim.x + threadIdx.x;
    const size_t total = (size_t)N_NODES * HDIM / 8;
    if (i >= total) return;
    const float4 a = reinterpret_cast<const float4*>(x)[2 * i];
    const float4 b = reinterpret_cast<const float4*>(x)[2 * i + 1];
    int4 r;
    __half2* h = reinterpret_cast<__half2*>(&r);
    h[0] = __floats2half2_rn(a.x, a.y);
    h[1] = __floats2half2_rn(a.z, a.w);
    h[2] = __floats2half2_rn(b.x, b.y);
    h[3] = __floats2half2_rn(b.z, b.w);
    reinterpret_cast<int4*>(xh)[i] = r;
}

// ---------------------------------------------------------------------------
// CSR build step 1: histogram of destination degrees
// ---------------------------------------------------------------------------
__global__ void hist_kernel(const int* __restrict__ dst, int* __restrict__ deg) {
    int e = blockIdx.x * blockDim.x + threadIdx.x;
    if (e >= N_EDGES) return;
    atomicAdd(&deg[dst[e]], 1);
}

// ---------------------------------------------------------------------------
// CSR build step 2a: per-block inclusive scan of deg
// ---------------------------------------------------------------------------
__global__ void scan_local_kernel(const int* __restrict__ deg,
                                  int* __restrict__ inc,
                                  int* __restrict__ blockSums) {
    __shared__ int lds[SCAN_B];
    int i = blockIdx.x * SCAN_B + threadIdx.x;
    int v = (i < N_NODES) ? deg[i] : 0;
    lds[threadIdx.x] = v;
    __syncthreads();
    #pragma unroll
    for (int off = 1; off < SCAN_B; off <<= 1) {
        int t = (threadIdx.x >= off) ? lds[threadIdx.x - off] : 0;
        __syncthreads();
        lds[threadIdx.x] += t;
        __syncthreads();
    }
    if (i < N_NODES) inc[i] = lds[threadIdx.x];
    if (threadIdx.x == SCAN_B - 1) blockSums[blockIdx.x] = lds[SCAN_B - 1];
}

// ---------------------------------------------------------------------------
// CSR build step 2b: exclusive scan of the 391 block sums (single block)
// ---------------------------------------------------------------------------
__global__ void scan_blocks_kernel(int* __restrict__ blockSums) {
    __shared__ int lds[512];
    int v = (threadIdx.x < N_SCAN_BLOCKS) ? blockSums[threadIdx.x] : 0;
    lds[threadIdx.x] = v;
    __syncthreads();
    #pragma unroll
    for (int off = 1; off < 512; off <<= 1) {
        int t = ((int)threadIdx.x >= off) ? lds[threadIdx.x - off] : 0;
        __syncthreads();
        lds[threadIdx.x] += t;
        __syncthreads();
    }
    if (threadIdx.x < N_SCAN_BLOCKS)
        blockSums[threadIdx.x] = (threadIdx.x == 0) ? 0 : lds[threadIdx.x - 1];
}

// ---------------------------------------------------------------------------
// CSR build step 2c: rowptr (exclusive) + cursor copy
// ---------------------------------------------------------------------------
__global__ void finalize_kernel(const int* __restrict__ deg,
                                const int* __restrict__ inc,
                                const int* __restrict__ blockSums,
                                int* __restrict__ rowptr,
                                int* __restrict__ cursor) {
    int i = blockIdx.x * SCAN_B + threadIdx.x;
    if (i >= N_NODES) return;
    int ex = inc[i] - deg[i] + blockSums[i >> 8];
    rowptr[i] = ex;
    cursor[i] = ex;
    if (i == 0) rowptr[N_NODES] = N_EDGES;
}

// ---------------------------------------------------------------------------
// CSR build step 3: fill packed (src_row_offset, weight) per slot
// ---------------------------------------------------------------------------
__global__ void fill_kernel(const int* __restrict__ src,
                            const int* __restrict__ dst,
                            const float* __restrict__ ew,
                            int* __restrict__ cursor,
                            int2* __restrict__ epack) {
    int e = blockIdx.x * blockDim.x + threadIdx.x;
    if (e >= N_EDGES) return;
    int d = dst[e];
    int pos = atomicAdd(&cursor[d], 1);
    int2 p;
    p.x = src[e] * HDIM;                 // element offset of source row
    p.y = __float_as_int(ew[e]);
    epack[pos] = p;
}

// ---------------------------------------------------------------------------
// helpers: 8-dim fp16 fragments per lane (regular cached loads)
// ---------------------------------------------------------------------------
__device__ __forceinline__ void fma8_h(const __half* __restrict__ p, float w, float* S) {
    int4 r = *reinterpret_cast<const int4*>(p);       // 8 halves
    const __half2* h = reinterpret_cast<const __half2*>(&r);
    #pragma unroll
    for (int q = 0; q < 4; ++q) {
        float2 f = __half22float2(h[q]);
        S[2 * q + 0] += w * f.x;
        S[2 * q + 1] += w * f.y;
    }
}
__device__ __forceinline__ void load8_h(const __half* __restrict__ p, float* o) {
    int4 r = *reinterpret_cast<const int4*>(p);
    const __half2* h = reinterpret_cast<const __half2*>(&r);
    #pragma unroll
    for (int q = 0; q < 4; ++q) {
        float2 f = __half22float2(h[q]);
        o[2 * q + 0] = f.x;
        o[2 * q + 1] = f.y;
    }
}
__device__ __forceinline__ void store8_h(__half* __restrict__ p, const float* v) {
    int4 r;
    __half2* h = reinterpret_cast<__half2*>(&r);
    #pragma unroll
    for (int q = 0; q < 4; ++q)
        h[q] = __floats2half2_rn(v[2 * q + 0], v[2 * q + 1]);
    *reinterpret_cast<int4*>(p) = r;
}

// ---------------------------------------------------------------------------
// Fused propagate: 16 lanes per node (8 dims/lane), 4 nodes per wave,
// 16 nodes per 256-thread block; 4x unrolled fp16 gathers (16B/lane).
//   MODE 0 (k=1):     S = gather(xh);  write T1 = S
//   MODE 1 (k=2,3,4): S = gather(Tp1); write Tc = 2S - Tp2
//   MODE 2 (k=5):     S = gather(T4);  T5 = 2S - T3;
//                     o = c0*xh + c1*T1 + ... + c5*T5;
//                     group affine -> RMSNorm -> SiLU -> out (f32)
// ---------------------------------------------------------------------------
template <int MODE>
__global__ __launch_bounds__(256)
void prop_kernel(const __half* __restrict__ Tp1h,   // gather source
                 const __half* __restrict__ Tp2h,
                 const __half* __restrict__ xh,     // MODE 2 only
                 const int* __restrict__ rowptr,
                 const int2* __restrict__ epack,
                 const float* __restrict__ cheb,
                 __half* __restrict__ Tch,
                 const __half* __restrict__ T1h,    // MODE 2 only
                 const __half* __restrict__ T2h,    // MODE 2 only
                 float* __restrict__ out,
                 const float* __restrict__ gscale,
                 const float* __restrict__ gbias,
                 const float* __restrict__ rmsw) {
    int grp = threadIdx.x >> 4;                  // 16-lane group id within block
    int sub = threadIdx.x & 15;                  // lane within group
    int row = blockIdx.x * 16 + grp;
    if (row >= N_NODES) return;

    int beg = rowptr[row];
    int end = rowptr[row + 1];
    int d8 = sub * 8;                            // dim offset of this lane

    float S[8] = {0, 0, 0, 0, 0, 0, 0, 0};
    int j = beg;
    for (; j + 3 < end; j += 4) {
        int2 e0 = epack[j], e1 = epack[j + 1], e2 = epack[j + 2], e3 = epack[j + 3];
        float w0 = __int_as_float(e0.y), w1 = __int_as_float(e1.y);
        float w2 = __int_as_float(e2.y), w3 = __int_as_float(e3.y);
        fma8_h(Tp1h + e0.x + d8, w0, S);
        fma8_h(Tp1h + e1.x + d8, w1, S);
        fma8_h(Tp1h + e2.x + d8, w2, S);
        fma8_h(Tp1h + e3.x + d8, w3, S);
    }
    for (; j < end; ++j) {
        int2 e0 = epack[j];
        float w = __int_as_float(e0.y);
        fma8_h(Tp1h + e0.x + d8, w, S);
    }

    size_t off = (size_t)row * HDIM + d8;
    int g = sub >> 2;                            // group index (32 dims per group)

    if (MODE == 0) {
        store8_h(Tch + off, S);
    } else if (MODE == 1) {
        float p[8];
        load8_h(Tp2h + off, p);
        float t[8];
        #pragma unroll
        for (int q = 0; q < 8; ++q) t[q] = 2.0f * S[q] - p[q];
        store8_h(Tch + off, t);
    } else {
        // final: full polynomial sum + epilogue
        float t3[8], t1[8], t2[8], t4[8], xr[8];
        load8_h(Tp2h + off, t3);       // T3 row
        load8_h(T1h + off, t1);
        load8_h(T2h + off, t2);
        load8_h(Tp1h + off, t4);       // T4 row (gather source this step)
        load8_h(xh + off, xr);

        float c0 = cheb[g * KP1 + 0], c1 = cheb[g * KP1 + 1], c2 = cheb[g * KP1 + 2];
        float c3 = cheb[g * KP1 + 3], c4 = cheb[g * KP1 + 4], c5 = cheb[g * KP1 + 5];
        float sc = gscale[g];
        float bi = gbias[g];

        float o[8];
        float ss = 0.0f;
        #pragma unroll
        for (int q = 0; q < 8; ++q) {
            float t5 = 2.0f * S[q] - t3[q];
            float v = c0 * xr[q] + c1 * t1[q] + c2 * t2[q] + c3 * t3[q]
                    + c4 * t4[q] + c5 * t5;
            v = v * sc + bi;
            o[q] = v;
            ss += v * v;
        }
        // reduce over the 16 lanes of this group (masks 1,2,4,8 stay in-group)
        #pragma unroll
        for (int m = 1; m < 16; m <<= 1)
            ss += __shfl_xor(ss, m, 64);
        float r = rsqrtf(ss * (1.0f / HDIM) + RMS_EPS);

        float4 wa = *reinterpret_cast<const float4*>(rmsw + d8);
        float4 wb = *reinterpret_cast<const float4*>(rmsw + d8 + 4);
        float wv[8] = {wa.x, wa.y, wa.z, wa.w, wb.x, wb.y, wb.z, wb.w};
        float res[8];
        #pragma unroll
        for (int q = 0; q < 8; ++q) {
            float a = o[q] * r * wv[q];
            res[q] = a / (1.0f + expf(-a));
        }
        float4 ra = {res[0], res[1], res[2], res[3]};
        float4 rb = {res[4], res[5], res[6], res[7]};
        *reinterpret_cast<float4*>(out + off) = ra;
        *reinterpret_cast<float4*>(out + off + 4) = rb;
    }
}

// ---------------------------------------------------------------------------
extern "C" void kernel_launch(void* const* d_in, const int* in_sizes, int n_in,
                              void* d_out, int out_size, void* d_ws, size_t ws_size,
                              hipStream_t stream) {
    const float* x      = (const float*)d_in[0];
    const float* ew     = (const float*)d_in[1];
    const float* cheb   = (const float*)d_in[2];
    const float* gscale = (const float*)d_in[3];
    const float* gbias  = (const float*)d_in[4];
    const float* rmsw   = (const float*)d_in[5];
    const int*   eidx   = (const int*)d_in[6];
    const int*   src    = eidx;               // edge_index[0]
    const int*   dst    = eidx + N_EDGES;     // edge_index[1]
    float* out = (float*)d_out;

    // workspace layout
    const size_t NH = (size_t)N_NODES * HDIM;
    __half* xh  = (__half*)d_ws;
    __half* T1  = xh + NH;
    __half* T2  = T1 + NH;
    __half* T3  = T2 + NH;
    __half* T4  = T3 + NH;
    int2*  epack    = (int2*)(T4 + NH);           // E entries (8B aligned)
    int*   deg      = (int*)(epack + N_EDGES);
    int*   inc      = deg + N_NODES;
    int*   rowptr   = inc + N_NODES;              // N+1
    int*   cursor   = rowptr + N_NODES + 1;
    int*   blockSums= cursor + N_NODES;           // 512

    const int TB = 256;
    const int edge_blocks = (N_EDGES + TB - 1) / TB;    // 1563
    const int conv_blocks = (int)((NH / 8 + TB - 1) / TB); // 6250
    const int prop_blocks = (N_NODES + 15) / 16;        // 6250

    // ---- x -> fp16 + CSR build (by destination) ----
    x2h_kernel<<<conv_blocks, TB, 0, stream>>>(x, xh);
    hipMemsetAsync(deg, 0, N_NODES * sizeof(int), stream);
    hist_kernel<<<edge_blocks, TB, 0, stream>>>(dst, deg);
    scan_local_kernel<<<N_SCAN_BLOCKS, SCAN_B, 0, stream>>>(deg, inc, blockSums);
    scan_blocks_kernel<<<1, 512, 0, stream>>>(blockSums);
    finalize_kernel<<<N_SCAN_BLOCKS, SCAN_B, 0, stream>>>(deg, inc, blockSums, rowptr, cursor);
    fill_kernel<<<edge_blocks, TB, 0, stream>>>(src, dst, ew, cursor, epack);

    // ---- fused Chebyshev propagates (all fp16) ----
    // k=1: T1 = prop(xh)
    prop_kernel<0><<<prop_blocks, TB, 0, stream>>>(xh, nullptr, nullptr, rowptr, epack,
                                                   cheb, T1, nullptr, nullptr,
                                                   out, gscale, gbias, rmsw);
    // k=2: T2 = 2*prop(T1) - xh
    prop_kernel<1><<<prop_blocks, TB, 0, stream>>>(T1, xh, nullptr, rowptr, epack,
                                                   cheb, T2, nullptr, nullptr,
                                                   out, gscale, gbias, rmsw);
    // k=3: T3 = 2*prop(T2) - T1
    prop_kernel<1><<<prop_blocks, TB, 0, stream>>>(T2, T1, nullptr, rowptr, epack,
                                                   cheb, T3, nullptr, nullptr,
                                                   out, gscale, gbias, rmsw);
    // k=4: T4 = 2*prop(T3) - T2
    prop_kernel<1><<<prop_blocks, TB, 0, stream>>>(T3, T2, nullptr, rowptr, epack,
                                                   cheb, T4, nullptr, nullptr,
                                                   out, gscale, gbias, rmsw);
    // k=5: T5 = 2*prop(T4) - T3; out = silu(rms(gaffine(sum c_k T_k)))
    prop_kernel<2><<<prop_blocks, TB, 0, stream>>>(T4, T3, xh, rowptr, epack,
                                                   cheb, nullptr, T1, T2,
                                                   out, gscale, gbias, rmsw);
}